// Round 9
// baseline (214.104 us; speedup 1.0000x reference)
//
#include <hip/hip_runtime.h>
#include <hip/hip_bf16.h>
#include <math.h>

typedef __attribute__((ext_vector_type(8))) short bfrag;   // 8 bf16 (16B)
typedef __attribute__((ext_vector_type(4))) float ffrag;   // mfma acc
typedef __attribute__((ext_vector_type(4))) float f4v;

#define C3 1536   // 3*H*D
#define PS 24     // P LDS row stride (shorts): 48B rows, 16B-aligned

__device__ __forceinline__ unsigned short f2bf(float f) {
    unsigned u = __float_as_uint(f);
    return (unsigned short)((u + 0x7FFFu + ((u >> 16) & 1u)) >> 16);  // RNE
}
__device__ __forceinline__ float bf2f(unsigned short s) {
    return __uint_as_float(((unsigned)s) << 16);
}

// sum over the 16 lanes of a DPP row: quad_perm xor1, xor2 + row_ror:4 + row_ror:8
__device__ __forceinline__ float row16_sum(float x) {
    int v;
    v = __builtin_amdgcn_update_dpp(0, __float_as_int(x), 0xB1, 0xF, 0xF, true);
    x += __int_as_float(v);
    v = __builtin_amdgcn_update_dpp(0, __float_as_int(x), 0x4E, 0xF, 0xF, true);
    x += __int_as_float(v);
    v = __builtin_amdgcn_update_dpp(0, __float_as_int(x), 0x124, 0xF, 0xF, true);
    x += __int_as_float(v);
    v = __builtin_amdgcn_update_dpp(0, __float_as_int(x), 0x128, 0xF, 0xF, true);
    x += __int_as_float(v);
    return x;
}

// ---------- kernel 1: cqkv bf16 table (cq pre-scaled by 1/8, blocks 0..1535)
//            + pbf bf16 [s*8+h][l][d] for s=pq',pk,pv (blocks 1536..1631) + gbtab ----------
__global__ __launch_bounds__(256) void precompute_kernel(
    const float* __restrict__ char_emb, const float* __restrict__ Wc, const float* __restrict__ bc,
    const float* __restrict__ Wp, const float* __restrict__ bp,
    const float* __restrict__ gamma, const float* __restrict__ beta,
    unsigned short* __restrict__ cqkv, unsigned short* __restrict__ pbf,
    float* __restrict__ gbtab)
{
    const int b = blockIdx.x;
    const int t = threadIdx.x;
    if (b < 1536) {
        const int mt = b / 6;
        const int nt = b - mt * 6;
        const int m0 = mt * 8;
        const int c = nt * 256 + t;
        const float qs = (c < 512) ? 0.125f : 1.f;   // bake 1/TEMP into q (exact in bf16)
        const float bias = bc[c];
        float acc[8];
        #pragma unroll
        for (int r = 0; r < 8; ++r) acc[r] = bias;
        #pragma unroll 16
        for (int dd = 0; dd < 64; ++dd) {
            const float wv = Wc[dd * C3 + c];           // per-lane, coalesced, L2-hot
            #pragma unroll
            for (int r = 0; r < 8; ++r)
                acc[r] = fmaf(char_emb[(m0 + r) * 64 + dd], wv, acc[r]);  // uniform -> s_load
        }
        #pragma unroll
        for (int r = 0; r < 8; ++r)
            cqkv[(size_t)(m0 + r) * C3 + c] = f2bf(acc[r] * qs);
    } else {                             // pbf: one (l, cc) pair per block
        const int e = b - 1536;
        const int l = e / 6;
        const int cc = e - l * 6;
        if (b == 1536 && t < 64) {       // gbtab[n][0..3]=gamma dt, [4..7]=beta dt
            #pragma unroll
            for (int dt = 0; dt < 4; ++dt) {
                gbtab[t * 8 + dt]     = gamma[dt * 16 + t];
                gbtab[t * 8 + 4 + dt] = beta[dt * 16 + t];
            }
        }
        __shared__ float spos[64];
        if (t < 64) {
            const int f = t & 31;
            const float inv = exp2f(-(float)f * 0.41524101186092034f);
            const float ph = (float)l * inv;
            spos[t] = (t < 32) ? cosf(ph) : sinf(ph);
        }
        __syncthreads();
        const int c = t + cc * 256;
        float acc = bp[c];
        #pragma unroll
        for (int dd = 0; dd < 64; ++dd)
            acc = fmaf(spos[dd], Wp[dd * C3 + c], acc);
        const float qs = (c < 512) ? 0.125f : 1.f;
        // s = c>>9 (0=pq',1=pk,2=pv), h = (c>>6)&7, d = c&63
        pbf[((c >> 9) * 8 + ((c >> 6) & 7)) * 1024 + l * 64 + (c & 63)] = f2bf(acc * qs);
    }
}

// ---------- kernel 2: wave-per-(word,head) attention + LN + pool (NO barriers) ----------
__global__ __launch_bounds__(256, 8) void attn_kernel(
    const unsigned short* __restrict__ cqkv, const unsigned short* __restrict__ pbf,
    const int* __restrict__ char_code, const float* __restrict__ gbtab,
    float* __restrict__ pooled)
{
    __shared__ __attribute__((aligned(16))) unsigned short sVt[4 * 1024];   // per-wave 2KB
    __shared__ __attribute__((aligned(16))) unsigned short sP[4 * 16 * PS]; // per-wave 768B

    const int t = threadIdx.x;
    const int lane = t & 63;
    const int wid = t >> 6;
    const int gw = blockIdx.x * 4 + wid;
    const int w = gw >> 3;
    const int h = gw & 7;
    const int quad = lane >> 4;
    const int n = lane & 15;

    const int code = char_code[w * 16 + n];
    const bool kvalid = (code != 0);
    const unsigned long long msk = __ballot(kvalid);
    const int nv = __popcll(msk & 0xFFFFull);

    const f4v g4 = *(const f4v*)(gbtab + n * 8);
    const f4v b4 = *(const f4v*)(gbtab + n * 8 + 4);

    // ---- stage V' = bf16(cv + pv) into wave-private swizzled tile (fused, no vtab) ----
    unsigned short* vt = sVt + wid * 1024;
    {
        const unsigned short* cvp = cqkv + (size_t)code * C3 + 1024 + h * 64;
        const unsigned short* pvp = pbf + (16 + h) * 1024 + n * 64;   // pv row l=n
        #pragma unroll
        for (int cc = 0; cc < 2; ++cc) {
            const int d8 = quad + cc * 4;
            const bfrag cv = *(const bfrag*)(cvp + d8 * 8);
            const bfrag pv = *(const bfrag*)(pvp + d8 * 8);
            #pragma unroll
            for (int j = 0; j < 8; ++j) {
                const float f = bf2f((unsigned short)cv[j]) + bf2f((unsigned short)pv[j]);
                const unsigned u = __float_as_uint(f) + 0x8000u;   // round-half-up to bf16
                const int d = d8 * 8 + j;
                const int e = ((d >> 4) * 2 + (n >> 3)) * 128
                            + ((d & 15) ^ ((n >> 3) << 2)) * 8 + (n & 7);
                vt[e] = (unsigned short)(u >> 16);
            }
        }
    }

    // ---- S = cq'·ck + cq'·pk + ck·pq' + pq'·pk  (1/TEMP pre-baked into q) ----
    ffrag accS = {0.f, 0.f, 0.f, 0.f};
    {
        const unsigned short* cbase = cqkv + (size_t)code * C3 + h * 64;
        const unsigned short* pq = pbf + h * 1024 + n * 64;
        const unsigned short* pk = pbf + (8 + h) * 1024 + n * 64;
        #pragma unroll
        for (int cc = 0; cc < 2; ++cc) {
            const int off = quad * 8 + cc * 32;
            const bfrag cqF = *(const bfrag*)(cbase + off);
            const bfrag ckF = *(const bfrag*)(cbase + 512 + off);
            const bfrag pqF = *(const bfrag*)(pq + off);
            const bfrag pkF = *(const bfrag*)(pk + off);
            accS = __builtin_amdgcn_mfma_f32_16x16x32_bf16(cqF, ckF, accS, 0, 0, 0);
            accS = __builtin_amdgcn_mfma_f32_16x16x32_bf16(cqF, pkF, accS, 0, 0, 0);
            accS = __builtin_amdgcn_mfma_f32_16x16x32_bf16(ckF, pqF, accS, 0, 0, 0);
            accS = __builtin_amdgcn_mfma_f32_16x16x32_bf16(pqF, pkF, accS, 0, 0, 0);
        }
    }

    // ---- softmax (no max-sub, logits ~1e-5), UNNORMALIZED P (1/sm cancels in LN) ----
    unsigned short* pt = sP + wid * 16 * PS;
    #pragma unroll
    for (int r = 0; r < 4; ++r) {
        const float pr = kvalid ? __expf(accS[r]) : 0.f;
        pt[(quad * 4 + r) * PS + n] = f2bf(pr);
    }

    // ---- O = P V  (K=16 zero-padded: quads 2,3 use zero A-frag) ----
    bfrag ap;
    #pragma unroll
    for (int j = 0; j < 8; ++j) ap[j] = 0;
    if (quad < 2) ap = *(const bfrag*)(pt + n * PS + quad * 8);
    const int q2 = quad & 1;
    ffrag accO[4];
    #pragma unroll
    for (int dt = 0; dt < 4; ++dt) { ffrag z = {0.f,0.f,0.f,0.f}; accO[dt] = z; }
    #pragma unroll
    for (int dt = 0; dt < 4; ++dt) {
        const bfrag bv = *(const bfrag*)(vt + (dt * 2 + q2) * 128 + (n ^ (q2 << 2)) * 8);
        accO[dt] = __builtin_amdgcn_mfma_f32_16x16x32_bf16(ap, bv, accO[dt], 0, 0, 0);
    }
    // row sums sm[i] via ones-MFMA: broadcast over n in C-layout
    bfrag onesf;
    #pragma unroll
    for (int j = 0; j < 8; ++j) onesf[j] = (short)0x3F80;
    ffrag accE = {0.f, 0.f, 0.f, 0.f};
    accE = __builtin_amdgcn_mfma_f32_16x16x32_bf16(ap, onesf, accE, 0, 0, 0);

    // ---- LayerNorm over D (O = sm * O_ref; eps scaled by sm^2) + masked pool over i ----
    float ps1[4], ps2[4];
    #pragma unroll
    for (int r = 0; r < 4; ++r) {
        ps1[r] = accO[0][r] + accO[1][r] + accO[2][r] + accO[3][r];
        ps2[r] = accO[0][r]*accO[0][r] + accO[1][r]*accO[1][r]
               + accO[2][r]*accO[2][r] + accO[3][r]*accO[3][r];
        ps1[r] = row16_sum(ps1[r]);
        ps2[r] = row16_sum(ps2[r]);
    }
    float pool[4] = {0.f, 0.f, 0.f, 0.f};
    #pragma unroll
    for (int r = 0; r < 4; ++r) {
        const float mu   = ps1[r] * 0.015625f;
        const float var  = fmaxf(ps2[r] * 0.015625f - mu * mu, 0.f);
        const float rstd = rsqrtf(var + accE[r] * accE[r] * 1e-5f);
        const float iv = ((msk >> (quad * 4 + r)) & 1ull) ? 1.f : 0.f;
        #pragma unroll
        for (int dt = 0; dt < 4; ++dt)
            pool[dt] += iv * fmaf((accO[dt][r] - mu) * rstd, g4[dt], b4[dt]);
    }
    #pragma unroll
    for (int xm = 16; xm <= 32; xm <<= 1) {
        #pragma unroll
        for (int dt = 0; dt < 4; ++dt) pool[dt] += __shfl_xor(pool[dt], xm);
    }
    if (quad == 0) {
        const float invnv = 1.f / (float)nv;
        f4v o;
        #pragma unroll
        for (int dt = 0; dt < 4; ++dt) o[dt] = pool[dt] * invnv;
        *(f4v*)(pooled + (size_t)w * 512 + h * 64 + n * 4) = o;   // [w][h][n][dt]
    }
}

// ---------- kernel 3: per-name fused MLP + word average (block per name, inline prefix) ----------
__global__ __launch_bounds__(128) void mlp_avg_kernel(
    const float* __restrict__ pooled, const int* __restrict__ word_code,
    const int* __restrict__ n_words,
    const float* __restrict__ W1, const float* __restrict__ b1,
    const float* __restrict__ W2, const float* __restrict__ b2,
    float* __restrict__ out)
{
    __shared__ float sPool[512];
    __shared__ float sHid[64 * 17];
    __shared__ float sWb[280];   // W1(128) b1(16) W2(128) b2(8)
    __shared__ int sred[128];
    const int nm = blockIdx.x;
    const int t = threadIdx.x;
    sWb[t] = W1[t];
    sWb[144 + t] = W2[t];
    if (t < 16) sWb[128 + t] = b1[t];
    if (t < 8)  sWb[272 + t] = b2[t];

    // inline exclusive prefix: off = sum_{i<nm} n_words[i]
    int part = 0;
    for (int i = t; i < nm; i += 128) part += n_words[i];
    sred[t] = part;
    __syncthreads();
    for (int s = 64; s > 0; s >>= 1) {
        if (t < s) sred[t] += sred[t + s];
        __syncthreads();
    }
    const int off = sred[0];
    const int cnt = n_words[nm];

    const int d = t & 63, o4 = (t >> 6) * 4;
    const int dmap = (d & 15) * 4 + (d >> 4);   // pooled layout [h][n][dt]
    float xacc[4] = {0.f, 0.f, 0.f, 0.f};

    for (int r = 0; r < cnt; ++r) {
        const int wc = word_code[off + r];
        __syncthreads();
        *(f4v*)(sPool + t * 4) = *(const f4v*)(pooled + (size_t)wc * 512 + t * 4);
        __syncthreads();
        if (t < 64) {
            float pl[8];
            #pragma unroll
            for (int hh = 0; hh < 8; ++hh) pl[hh] = sPool[hh * 64 + dmap];
            #pragma unroll
            for (int c = 0; c < 16; ++c) {
                float hs = sWb[128 + c];
                #pragma unroll
                for (int hh = 0; hh < 8; ++hh) hs = fmaf(pl[hh], sWb[hh * 16 + c], hs);
                sHid[t * 17 + c] = fmaxf(hs, 0.f);
            }
        }
        __syncthreads();
        #pragma unroll
        for (int c = 0; c < 16; ++c) {
            const float hc = sHid[d * 17 + c];
            #pragma unroll
            for (int oo = 0; oo < 4; ++oo)
                xacc[oo] = fmaf(hc, sWb[144 + c * 8 + o4 + oo], xacc[oo]);
        }
    }
    const float inv = 1.f / (float)cnt;
    f4v res;
    #pragma unroll
    for (int oo = 0; oo < 4; ++oo) res[oo] = xacc[oo] * inv + sWb[272 + o4 + oo];
    *(f4v*)(out + (size_t)nm * 512 + d * 8 + o4) = res;
}

extern "C" void kernel_launch(void* const* d_in, const int* in_sizes, int n_in,
                              void* d_out, int out_size, void* d_ws, size_t ws_size,
                              hipStream_t stream) {
    (void)in_sizes; (void)n_in; (void)out_size; (void)ws_size;
    const float* char_emb = (const float*)d_in[0];
    const float* Wc    = (const float*)d_in[1];
    const float* bc    = (const float*)d_in[2];
    const float* Wp    = (const float*)d_in[3];
    const float* bp    = (const float*)d_in[4];
    const float* gamma = (const float*)d_in[5];
    const float* beta  = (const float*)d_in[6];
    const float* W1    = (const float*)d_in[7];
    const float* b1    = (const float*)d_in[8];
    const float* W2    = (const float*)d_in[9];
    const float* b2    = (const float*)d_in[10];
    const int* char_code = (const int*)d_in[11];
    const int* word_code = (const int*)d_in[12];
    const int* n_words   = (const int*)d_in[13];   // harness passes ints as int32

    char* ws = (char*)d_ws;
    unsigned short* cqkv = (unsigned short*)ws;                        //  6,291,456 B
    unsigned short* pbf  = (unsigned short*)(ws + 6291456);            //     49,152 B
    float* pooled = (float*)(ws + 6340608);                            // 16,777,216 B
    float* gbtab  = (float*)(ws + 23117824);                           //      2,048 B
    float* out = (float*)d_out;

    precompute_kernel<<<1632, 256, 0, stream>>>(char_emb, Wc, bc, Wp, bp, gamma, beta,
                                                cqkv, pbf, gbtab);
    attn_kernel<<<16384, 256, 0, stream>>>(cqkv, pbf, char_code, gbtab, pooled);
    mlp_avg_kernel<<<2048, 128, 0, stream>>>(pooled, word_code, n_words,
                                             W1, b1, W2, b2, out);
}

// Round 10
// 200.520 us; speedup vs baseline: 1.0677x; 1.0677x over previous
//
#include <hip/hip_runtime.h>
#include <hip/hip_bf16.h>
#include <math.h>

typedef __attribute__((ext_vector_type(8))) short bfrag;   // 8 bf16 (16B)
typedef __attribute__((ext_vector_type(4))) float ffrag;   // mfma acc
typedef __attribute__((ext_vector_type(4))) float f4v;
typedef __attribute__((ext_vector_type(2))) float f2v;

#define C3 1536   // 3*H*D
#define PS 24     // P LDS row stride (shorts)

__device__ __forceinline__ unsigned short f2bf(float f) {
    unsigned u = __float_as_uint(f);
    return (unsigned short)((u + 0x7FFFu + ((u >> 16) & 1u)) >> 16);  // RNE
}

// sum over the 16 lanes of a DPP row
__device__ __forceinline__ float row16_sum(float x) {
    int v;
    v = __builtin_amdgcn_update_dpp(0, __float_as_int(x), 0xB1, 0xF, 0xF, true);
    x += __int_as_float(v);
    v = __builtin_amdgcn_update_dpp(0, __float_as_int(x), 0x4E, 0xF, 0xF, true);
    x += __int_as_float(v);
    v = __builtin_amdgcn_update_dpp(0, __float_as_int(x), 0x124, 0xF, 0xF, true);
    x += __int_as_float(v);
    v = __builtin_amdgcn_update_dpp(0, __float_as_int(x), 0x128, 0xF, 0xF, true);
    x += __int_as_float(v);
    return x;
}

// ---------- kernel 1: cqkv bf16 (cq pre-scaled 1/8, blocks 0..1535)
//            + pq'/pk bf16 rows + pv B-frag table + gbtab (blocks 1536..1631) ----------
__global__ __launch_bounds__(256) void precompute_kernel(
    const float* __restrict__ char_emb, const float* __restrict__ Wc, const float* __restrict__ bc,
    const float* __restrict__ Wp, const float* __restrict__ bp,
    const float* __restrict__ gamma, const float* __restrict__ beta,
    unsigned short* __restrict__ cqkv, unsigned short* __restrict__ pbf,
    unsigned short* __restrict__ pvb, float* __restrict__ gbtab)
{
    const int b = blockIdx.x;
    const int t = threadIdx.x;
    if (b < 1536) {
        const int mt = b / 6;
        const int nt = b - mt * 6;
        const int m0 = mt * 8;
        const int c = nt * 256 + t;
        const float qs = (c < 512) ? 0.125f : 1.f;   // bake 1/TEMP into q
        const float bias = bc[c];
        float acc[8];
        #pragma unroll
        for (int r = 0; r < 8; ++r) acc[r] = bias;
        #pragma unroll 16
        for (int dd = 0; dd < 64; ++dd) {
            const float wv = Wc[dd * C3 + c];
            #pragma unroll
            for (int r = 0; r < 8; ++r)
                acc[r] = fmaf(char_emb[(m0 + r) * 64 + dd], wv, acc[r]);  // uniform -> s_load
        }
        #pragma unroll
        for (int r = 0; r < 8; ++r)
            cqkv[(size_t)(m0 + r) * C3 + c] = f2bf(acc[r] * qs);
    } else {                             // one (l, cc) pair per block
        const int e = b - 1536;
        const int l = e / 6;
        const int cc = e - l * 6;
        if (b == 1536 && t < 64) {       // gbtab[n][0..3]=gamma dt, [4..7]=beta dt
            #pragma unroll
            for (int dt = 0; dt < 4; ++dt) {
                gbtab[t * 8 + dt]     = gamma[dt * 16 + t];
                gbtab[t * 8 + 4 + dt] = beta[dt * 16 + t];
            }
        }
        __shared__ float spos[64];
        if (t < 64) {
            const int f = t & 31;
            const float inv = exp2f(-(float)f * 0.41524101186092034f);
            const float ph = (float)l * inv;
            spos[t] = (t < 32) ? cosf(ph) : sinf(ph);
        }
        __syncthreads();
        const int c = t + cc * 256;
        float acc = bp[c];
        #pragma unroll
        for (int dd = 0; dd < 64; ++dd)
            acc = fmaf(spos[dd], Wp[dd * C3 + c], acc);
        if (c < 1024) {                  // pq'/pk rows: [(s*8+h)][l][d]
            const float qs = (c < 512) ? 0.125f : 1.f;
            pbf[(c >> 6) * 1024 + l * 64 + (c & 63)] = f2bf(acc * qs);
        } else {                         // pv B-frag table: [h][dt][q2][n][j], k=q2*8+j=l, col=n=d&15
            const int h = (c >> 6) & 7, d = c & 63;
            pvb[((h * 4 + (d >> 4)) * 2 + (l >> 3)) * 128 + (d & 15) * 8 + (l & 7)] = f2bf(acc);
        }
    }
}

// ---------- kernel 2: block-per-word attention (2 heads/wave) + LN + pool + MLP ----------
__global__ __launch_bounds__(256, 4) void attn_kernel(
    const unsigned short* __restrict__ cqkv, const unsigned short* __restrict__ pbf,
    const unsigned short* __restrict__ pvb, const int* __restrict__ char_code,
    const float* __restrict__ gbtab,
    const float* __restrict__ W1, const float* __restrict__ b1,
    const float* __restrict__ W2, const float* __restrict__ b2,
    float* __restrict__ x)
{
    __shared__ __attribute__((aligned(16))) unsigned short sVt[8 * 1024];   // cv tiles, per-head
    __shared__ __attribute__((aligned(16))) unsigned short sP[8 * 16 * PS];
    __shared__ float sPool[512];
    __shared__ float sHid[64 * 17];
    __shared__ float sWb[280];

    const int t = threadIdx.x;
    const int lane = t & 63;
    const int wid = t >> 6;
    const int w = blockIdx.x;
    const int quad = lane >> 4;
    const int n = lane & 15;
    const int q2 = quad & 1;

    if (t < 128) { sWb[t] = W1[t]; sWb[144 + t] = W2[t]; }
    else if (t < 144) sWb[t] = b1[t - 128];
    else if (t < 152) sWb[272 + (t - 144)] = b2[t - 144];

    const int code = char_code[w * 16 + n];
    const bool kvalid = (code != 0);
    const unsigned long long msk = __ballot(kvalid);
    const int nv = __popcll(msk & 0xFFFFull);

    const f4v g4 = *(const f4v*)(gbtab + n * 8);
    const f4v b4 = *(const f4v*)(gbtab + n * 8 + 4);

    // ---- stage cv (raw bf16 copy, rows shared with S-phase) for both heads ----
    #pragma unroll
    for (int c2 = 0; c2 < 2; ++c2) {
        const int h = wid + c2 * 4;
        unsigned short* vt = sVt + h * 1024;
        const unsigned short* cvp = cqkv + (size_t)code * C3 + 1024 + h * 64;
        #pragma unroll
        for (int cc = 0; cc < 2; ++cc) {
            const int d8 = quad + cc * 4;
            const bfrag cv = *(const bfrag*)(cvp + d8 * 8);
            #pragma unroll
            for (int j = 0; j < 8; ++j) {
                const int d = d8 * 8 + j;
                const int e = ((d >> 4) * 2 + (n >> 3)) * 128
                            + ((d & 15) ^ ((n >> 3) << 2)) * 8 + (n & 7);
                vt[e] = (unsigned short)cv[j];
            }
        }
    }

    // ---- S = cq'·ck + cq'·pk + ck·pq' + pq'·pk for both heads ----
    ffrag accS[2];
    #pragma unroll
    for (int c2 = 0; c2 < 2; ++c2) { ffrag z = {0.f,0.f,0.f,0.f}; accS[c2] = z; }
    #pragma unroll
    for (int c2 = 0; c2 < 2; ++c2) {
        const int h = wid + c2 * 4;
        const unsigned short* cbase = cqkv + (size_t)code * C3 + h * 64;
        const unsigned short* pq = pbf + h * 1024 + n * 64;
        const unsigned short* pk = pbf + (8 + h) * 1024 + n * 64;
        #pragma unroll
        for (int cc = 0; cc < 2; ++cc) {
            const int off = quad * 8 + cc * 32;
            const bfrag cqF = *(const bfrag*)(cbase + off);
            const bfrag ckF = *(const bfrag*)(cbase + 512 + off);
            const bfrag pqF = *(const bfrag*)(pq + off);
            const bfrag pkF = *(const bfrag*)(pk + off);
            accS[c2] = __builtin_amdgcn_mfma_f32_16x16x32_bf16(cqF, ckF, accS[c2], 0, 0, 0);
            accS[c2] = __builtin_amdgcn_mfma_f32_16x16x32_bf16(cqF, pkF, accS[c2], 0, 0, 0);
            accS[c2] = __builtin_amdgcn_mfma_f32_16x16x32_bf16(ckF, pqF, accS[c2], 0, 0, 0);
            accS[c2] = __builtin_amdgcn_mfma_f32_16x16x32_bf16(pqF, pkF, accS[c2], 0, 0, 0);
        }
    }

    // ---- softmax (no max-sub; logits ~1e-5), UNNORMALIZED P ----
    #pragma unroll
    for (int c2 = 0; c2 < 2; ++c2) {
        const int h = wid + c2 * 4;
        unsigned short* pt = sP + h * 16 * PS;
        #pragma unroll
        for (int r = 0; r < 4; ++r) {
            const float pr = kvalid ? __expf(accS[c2][r]) : 0.f;
            pt[(quad * 4 + r) * PS + n] = f2bf(pr);
        }
    }

    bfrag onesf;
    #pragma unroll
    for (int j = 0; j < 8; ++j) onesf[j] = (short)0x3F80;

    // ---- O = P·cv (LDS) + P·pv (direct B-frag) ; sm via ones-MFMA ; LN + pool ----
    #pragma unroll
    for (int c2 = 0; c2 < 2; ++c2) {
        const int h = wid + c2 * 4;
        unsigned short* pt = sP + h * 16 * PS;
        unsigned short* vt = sVt + h * 1024;
        bfrag ap;
        #pragma unroll
        for (int j = 0; j < 8; ++j) ap[j] = 0;
        if (quad < 2) ap = *(const bfrag*)(pt + n * PS + quad * 8);
        ffrag accO[4];
        #pragma unroll
        for (int dt = 0; dt < 4; ++dt) { ffrag z = {0.f,0.f,0.f,0.f}; accO[dt] = z; }
        #pragma unroll
        for (int dt = 0; dt < 4; ++dt) {
            const bfrag bcv = *(const bfrag*)(vt + (dt * 2 + q2) * 128 + (n ^ (q2 << 2)) * 8);
            accO[dt] = __builtin_amdgcn_mfma_f32_16x16x32_bf16(ap, bcv, accO[dt], 0, 0, 0);
            const bfrag bpv = *(const bfrag*)(pvb + ((h * 4 + dt) * 2 + q2) * 128 + n * 8);
            accO[dt] = __builtin_amdgcn_mfma_f32_16x16x32_bf16(ap, bpv, accO[dt], 0, 0, 0);
        }
        ffrag accE = {0.f, 0.f, 0.f, 0.f};
        accE = __builtin_amdgcn_mfma_f32_16x16x32_bf16(ap, onesf, accE, 0, 0, 0);

        float ps1[4], ps2[4];
        #pragma unroll
        for (int r = 0; r < 4; ++r) {
            ps1[r] = accO[0][r] + accO[1][r] + accO[2][r] + accO[3][r];
            ps2[r] = accO[0][r]*accO[0][r] + accO[1][r]*accO[1][r]
                   + accO[2][r]*accO[2][r] + accO[3][r]*accO[3][r];
            ps1[r] = row16_sum(ps1[r]);
            ps2[r] = row16_sum(ps2[r]);
        }
        float pool[4] = {0.f, 0.f, 0.f, 0.f};
        #pragma unroll
        for (int r = 0; r < 4; ++r) {
            const float mu   = ps1[r] * 0.015625f;
            const float var  = fmaxf(ps2[r] * 0.015625f - mu * mu, 0.f);
            const float rstd = rsqrtf(var + accE[r] * accE[r] * 1e-5f);
            const float iv = ((msk >> (quad * 4 + r)) & 1ull) ? 1.f : 0.f;
            #pragma unroll
            for (int dt = 0; dt < 4; ++dt)
                pool[dt] += iv * fmaf((accO[dt][r] - mu) * rstd, g4[dt], b4[dt]);
        }
        #pragma unroll
        for (int xm = 16; xm <= 32; xm <<= 1) {
            #pragma unroll
            for (int dt = 0; dt < 4; ++dt) pool[dt] += __shfl_xor(pool[dt], xm);
        }
        if (quad == 0) {
            const float invnv = 1.f / (float)nv;
            #pragma unroll
            for (int dt = 0; dt < 4; ++dt)
                sPool[h * 64 + n * 4 + dt] = pool[dt] * invnv;   // [h][n][dt]
        }
    }
    __syncthreads();

    // ---- MLP: hidden per d (t<64), then 2 outputs per thread, coalesced 2KB store ----
    if (t < 64) {
        const int dmap = (t & 15) * 4 + (t >> 4);
        float pl[8];
        #pragma unroll
        for (int hh = 0; hh < 8; ++hh) pl[hh] = sPool[hh * 64 + dmap];
        #pragma unroll
        for (int c = 0; c < 16; ++c) {
            float hs = sWb[128 + c];
            #pragma unroll
            for (int hh = 0; hh < 8; ++hh) hs = fmaf(pl[hh], sWb[hh * 16 + c], hs);
            sHid[t * 17 + c] = fmaxf(hs, 0.f);
        }
    }
    __syncthreads();
    {
        const int d = t >> 2, o0 = (t & 3) * 2;
        float a0 = sWb[272 + o0], a1 = sWb[272 + o0 + 1];
        #pragma unroll
        for (int c = 0; c < 16; ++c) {
            const float hc = sHid[d * 17 + c];
            a0 = fmaf(hc, sWb[144 + c * 8 + o0], a0);
            a1 = fmaf(hc, sWb[144 + c * 8 + o0 + 1], a1);
        }
        f2v res; res[0] = a0; res[1] = a1;
        *(f2v*)(x + (size_t)w * 512 + t * 2) = res;
    }
}

// ---------- kernel 3: per-name word average (wave per name, no barriers) ----------
__global__ __launch_bounds__(256) void name_avg_kernel(
    const float* __restrict__ x, const int* __restrict__ word_code,
    const int* __restrict__ n_words, float* __restrict__ out)
{
    const int t = threadIdx.x;
    const int lane = t & 63;
    const int nm = blockIdx.x * 4 + (t >> 6);

    int part = 0;
    for (int i = lane; i < nm; i += 64) part += n_words[i];
    #pragma unroll
    for (int xm = 1; xm <= 32; xm <<= 1) part += __shfl_xor(part, xm);
    const int off = part;
    const int cnt = n_words[nm];

    f4v a0 = {0.f,0.f,0.f,0.f}, a1 = {0.f,0.f,0.f,0.f};
    for (int r = 0; r < cnt; ++r) {
        const int wc = word_code[off + r];
        const f4v u0 = *(const f4v*)(x + (size_t)wc * 512 + lane * 8);
        const f4v u1 = *(const f4v*)(x + (size_t)wc * 512 + lane * 8 + 4);
        #pragma unroll
        for (int k = 0; k < 4; ++k) { a0[k] += u0[k]; a1[k] += u1[k]; }
    }
    const float inv = 1.f / (float)cnt;
    #pragma unroll
    for (int k = 0; k < 4; ++k) { a0[k] *= inv; a1[k] *= inv; }
    *(f4v*)(out + (size_t)nm * 512 + lane * 8) = a0;
    *(f4v*)(out + (size_t)nm * 512 + lane * 8 + 4) = a1;
}

extern "C" void kernel_launch(void* const* d_in, const int* in_sizes, int n_in,
                              void* d_out, int out_size, void* d_ws, size_t ws_size,
                              hipStream_t stream) {
    (void)in_sizes; (void)n_in; (void)out_size; (void)ws_size;
    const float* char_emb = (const float*)d_in[0];
    const float* Wc    = (const float*)d_in[1];
    const float* bc    = (const float*)d_in[2];
    const float* Wp    = (const float*)d_in[3];
    const float* bp    = (const float*)d_in[4];
    const float* gamma = (const float*)d_in[5];
    const float* beta  = (const float*)d_in[6];
    const float* W1    = (const float*)d_in[7];
    const float* b1    = (const float*)d_in[8];
    const float* W2    = (const float*)d_in[9];
    const float* b2    = (const float*)d_in[10];
    const int* char_code = (const int*)d_in[11];
    const int* word_code = (const int*)d_in[12];
    const int* n_words   = (const int*)d_in[13];   // harness passes ints as int32

    char* ws = (char*)d_ws;
    unsigned short* cqkv = (unsigned short*)ws;                 //  6,291,456 B
    unsigned short* pbf  = (unsigned short*)(ws + 6291456);     //     32,768 B
    unsigned short* pvb  = (unsigned short*)(ws + 6324224);     //     16,384 B
    float* x     = (float*)(ws + 6340608);                      // 16,777,216 B
    float* gbtab = (float*)(ws + 23117824);                     //      2,048 B
    float* out = (float*)d_out;

    precompute_kernel<<<1632, 256, 0, stream>>>(char_emb, Wc, bc, Wp, bp, gamma, beta,
                                                cqkv, pbf, pvb, gbtab);
    attn_kernel<<<8192, 256, 0, stream>>>(cqkv, pbf, pvb, char_code, gbtab,
                                          W1, b1, W2, b2, x);
    name_avg_kernel<<<512, 256, 0, stream>>>(x, word_code, n_words, out);
}